// Round 8
// baseline (1383.336 us; speedup 1.0000x reference)
//
#include <hip/hip_runtime.h>
#include <hip/hip_fp16.h>
#include <cstdint>
#include <cstddef>

#define SEQ   128
#define BATCH 256
#define HDIM  1024
#define ODIM  128
#define NBLK  256

typedef _Float16 half_t;
typedef _Float16 half8 __attribute__((ext_vector_type(8)));
typedef float    f32x4 __attribute__((ext_vector_type(4)));
typedef unsigned long long u64;

// dynamic LDS layout (extern __shared__ + hipFuncSetAttribute -- R5-proven):
//   Bs (gate-o weights, f16)  at      0 .. 65536
//   P  (K-reduce, fp32)       at  65536 .. 131072
//   Hs (h staging, f16)       at 131072 .. 133120
//   icomm                     at 133120 .. 133184
#define LDS_P_OFF    65536
#define LDS_HS_OFF   131072
#define LDS_IC_OFF   133120
#define LDS_BYTES    133184

// ws: 129 fresh h buffers, then stepflags[128][8][32] ints, flags0[256], cnt[8]
#define HBUF_BYTES   524288
#define FLAGS_OFF    ((size_t)129 * HBUF_BYTES)  // 67,633,152
#define FLAGS0_OFF   (FLAGS_OFF + 131072)
#define CNT_OFF      (FLAGS0_OFF + 1024)
#define INIT_INTS    ((131072 + 1024 + 32) / 4)

__device__ __forceinline__ float sigmoidf_(float z) {
    return 1.0f / (1.0f + __expf(-z));
}
__device__ __forceinline__ float tanhf_(float z) {
    z = fminf(fmaxf(z, -30.0f), 30.0f);
    float e = __expf(2.0f * z);
    return (e - 1.0f) / (e + 1.0f);
}

// Zero flag/cnt region (ws re-poisoned to 0xAA before every timed call).
__global__ __launch_bounds__(256) void lstm_init(int* __restrict__ z) {
    const int i = blockIdx.x * 256 + threadIdx.x;
    if (i < INIT_INTS) z[i] = 0;
}

// ---------------------------------------------------------------------------
// Persistent LSTM. 256 blocks x 256 threads, 1 block/CU (130 KB LDS).
// Group of 32 blocks owns 32 batch rows; block slot s owns 32 hidden units
// x 4 gates. Weights: gates f,i,g in 192 VGPRs/lane (wave = K-quarter),
// gate o in 64 KB LDS (conflict-free layout).
// Sync flags ALWAYS use the R5-proven LLC protocol (relaxed agent-scope
// atomics = sc1, bypassing L1+L2 -- no cached-spin deadlock possible).
// Fast mode (each XCD hosts exactly 32 blocks): group = XCD and the h DATA
// uses normal cached stores, staying in the XCD-local L2 (L1 is write-
// through; vmcnt(0)+barrier before the flag leaves => same-XCD consumers
// that see the flag find h in the shared L2; fresh buffer per step => first
// touch, no staleness). Otherwise h also goes sc1 (exact R5 protocol).
// Mode decided once behind a one-time LLC grid barrier -- correctness never
// assumes XCD placement (G16).
// ---------------------------------------------------------------------------
__global__ __launch_bounds__(256, 1) void lstm_persist(
    const float* __restrict__ x,
    const float* __restrict__ Wfh, const float* __restrict__ Wih,
    const float* __restrict__ Wgh, const float* __restrict__ Woh,
    const float* __restrict__ Wfx, const float* __restrict__ Wix,
    const float* __restrict__ Wgx, const float* __restrict__ Wox,
    const float* __restrict__ bfx, const float* __restrict__ bix,
    const float* __restrict__ bgx, const float* __restrict__ box,
    const float* __restrict__ bfh, const float* __restrict__ bih,
    const float* __restrict__ bgh, const float* __restrict__ boh,
    const float* __restrict__ Wph, const float* __restrict__ bph,
    char* __restrict__ wsbase, float* __restrict__ out)
{
    extern __shared__ char smem[];
    half_t* Bs    = (half_t*)smem;
    float*  P     = (float*)(smem + LDS_P_OFF);
    half_t* Hs    = (half_t*)(smem + LDS_HS_OFF);
    int*    icomm = (int*)(smem + LDS_IC_OFF);

    int* stepflags = (int*)(wsbase + FLAGS_OFF);
    int* flags0    = (int*)(wsbase + FLAGS0_OFF);
    int* cnt       = (int*)(wsbase + CNT_OFF);

    const int tid  = threadIdx.x;
    const int blk  = blockIdx.x;
    const int w    = tid >> 6;
    const int lane = tid & 63;
    const int l15  = lane & 15;
    const int q    = lane >> 4;

    // ---- phase 0: XCD discovery, ticket, one-time grid barrier, mode ----
    if (tid == 0) {
        int xcd;
        asm volatile("s_getreg_b32 %0, hwreg(HW_REG_XCC_ID)" : "=s"(xcd));
        xcd &= 7;
        const int tk = atomicAdd(&cnt[xcd], 1);
        icomm[0] = xcd;
        icomm[1] = tk;
        __hip_atomic_store(&flags0[blk], 1, __ATOMIC_RELEASE,
                           __HIP_MEMORY_SCOPE_AGENT);
    }
    if (w == 0) {
        for (;;) {
            int ok = 1;
#pragma unroll
            for (int i = 0; i < 4; ++i)
                ok &= (__hip_atomic_load(&flags0[lane * 4 + i], __ATOMIC_RELAXED,
                                         __HIP_MEMORY_SCOPE_AGENT) == 1);
            if (__all(ok)) break;
            __builtin_amdgcn_s_sleep(8);
        }
        const int v = (lane < 8)
            ? __hip_atomic_load(&cnt[lane], __ATOMIC_RELAXED,
                                __HIP_MEMORY_SCOPE_AGENT) : 32;
        icomm[2] = __all(v == 32) ? 1 : 0;
    }
    __syncthreads();
    const int fast  = icomm[2];
    const int group = fast ? icomm[0] : (blk >> 5);
    const int slot  = fast ? icomm[1] : (blk & 31);
    const int m0    = group << 5;          // 32 batch rows
    const int ubase = slot << 5;           // 32 hidden units (x4 gates)
    const int k0    = w << 8;              // wave's K-quarter

    // ---- phase 1a: gates f,i,g fp32 -> f16 into registers ----
    // tile j: gate g=j>>1, unit-half j&1, rows ubase+(j&1)*16+l15;
    // frag (j,kk) = W[row][k0 + kk*32 + q*8 .. +8]
    half8 Breg[6][8];
    {
        const float* Wg[3] = {Wfh, Wih, Wgh};
#pragma unroll
        for (int j = 0; j < 6; ++j) {
            const float* wr = Wg[j >> 1]
                + (size_t)(ubase + ((j & 1) << 4) + l15) * HDIM + k0 + (q << 3);
#pragma unroll
            for (int kk = 0; kk < 8; ++kk) {
                const float4 v0 = *(const float4*)(wr + kk * 32);
                const float4 v1 = *(const float4*)(wr + kk * 32 + 4);
                half8 hv;
                hv[0] = (half_t)v0.x; hv[1] = (half_t)v0.y;
                hv[2] = (half_t)v0.z; hv[3] = (half_t)v0.w;
                hv[4] = (half_t)v1.x; hv[5] = (half_t)v1.y;
                hv[6] = (half_t)v1.z; hv[7] = (half_t)v1.w;
                Breg[j][kk] = hv;
            }
        }
    }
    // ---- phase 1b: gate o -> LDS, slot d = (((wq*2+jj)*8+kk)*4+qq)*16+l ----
    for (int d = tid; d < 4096; d += 256) {
        const int l = d & 15, qq = (d >> 4) & 3, kk = (d >> 6) & 7;
        const int jj = (d >> 9) & 1, wq = d >> 10;
        const float* src = Woh + (size_t)(ubase + (jj << 4) + l) * HDIM
                         + (wq << 8) + (kk << 5) + (qq << 3);
        const float4 v0 = *(const float4*)src;
        const float4 v1 = *(const float4*)(src + 4);
        half8 hv;
        hv[0] = (half_t)v0.x; hv[1] = (half_t)v0.y;
        hv[2] = (half_t)v0.z; hv[3] = (half_t)v0.w;
        hv[4] = (half_t)v1.x; hv[5] = (half_t)v1.y;
        hv[6] = (half_t)v1.z; hv[7] = (half_t)v1.w;
        *(half8*)(Bs + (size_t)d * 8) = hv;
    }

    // ---- epilogue constants: wave owns (mt_w = w>>1, p_w = w&1) ----
    const int mt_w = w >> 1, p_w = w & 1;
    const int u_e  = ubase + (p_w << 4) + l15;
    const float bf = bfx[u_e] + bfh[u_e], bi = bix[u_e] + bih[u_e];
    const float bg = bgx[u_e] + bgh[u_e], bo = box[u_e] + boh[u_e];
    const float wf = Wfx[u_e], wi = Wix[u_e], wg = Wgx[u_e], wo = Wox[u_e];
    f32x4 creg = {0.f, 0.f, 0.f, 0.f};

    __syncthreads();   // Bs ready

    for (int t = 0; t < SEQ; ++t) {
        const half_t* hin  = (const half_t*)(wsbase + (size_t)t * HBUF_BYTES);
        half_t*       hout = (half_t*)(wsbase + (size_t)(t + 1) * HBUF_BYTES);

        f32x4 acc[2][8] = {};
        if (t > 0) {
            const half_t* abase = hin + (size_t)(m0 + l15) * HDIM + k0 + (q << 3);
#pragma unroll
            for (int kk = 0; kk < 8; ++kk) {
                const half8 a0 = *(const half8*)(abase + kk * 32);
                const half8 a1 = *(const half8*)(abase + (16 * HDIM) + kk * 32);
                const half8 b6 = *(const half8*)(Bs +
                    (size_t)(((((w << 1) + 0) << 3 | kk) << 2 | q) << 4 | l15) * 8);
                const half8 b7 = *(const half8*)(Bs +
                    (size_t)(((((w << 1) + 1) << 3 | kk) << 2 | q) << 4 | l15) * 8);
#pragma unroll
                for (int j = 0; j < 6; ++j) {
                    acc[0][j] = __builtin_amdgcn_mfma_f32_16x16x32_f16(
                        a0, Breg[j][kk], acc[0][j], 0, 0, 0);
                    acc[1][j] = __builtin_amdgcn_mfma_f32_16x16x32_f16(
                        a1, Breg[j][kk], acc[1][j], 0, 0, 0);
                }
                acc[0][6] = __builtin_amdgcn_mfma_f32_16x16x32_f16(a0, b6, acc[0][6], 0, 0, 0);
                acc[1][6] = __builtin_amdgcn_mfma_f32_16x16x32_f16(a1, b6, acc[1][6], 0, 0, 0);
                acc[0][7] = __builtin_amdgcn_mfma_f32_16x16x32_f16(a0, b7, acc[0][7], 0, 0, 0);
                acc[1][7] = __builtin_amdgcn_mfma_f32_16x16x32_f16(a1, b7, acc[1][7], 0, 0, 0);
            }
        }

        // ---- cross-wave K-reduce via LDS P: write non-owned tiles ----
        // tile (mt,j) owned by wave (mt, j&1); slot [((mt*8+j)*4+src)*256+lane*4]
#pragma unroll
        for (int mt = 0; mt < 2; ++mt)
#pragma unroll
            for (int j = 0; j < 8; ++j)
                if (!(mt == mt_w && (j & 1) == p_w))
                    *(f32x4*)&P[(((mt << 3) + j) * 4 + w) * 256 + (lane << 2)]
                        = acc[mt][j];
        __syncthreads();

        // ---- owner sums its 4 gate-tiles + fused gate epilogue ----
        {
            f32x4 z[4];
#pragma unroll
            for (int g = 0; g < 4; ++g) {
                const int j = p_w + (g << 1);
                f32x4 s = acc[mt_w][j];
#pragma unroll
                for (int src = 0; src < 4; ++src)
                    if (src != w)
                        s += *(const f32x4*)
                            &P[(((mt_w << 3) + j) * 4 + src) * 256 + (lane << 2)];
                z[g] = s;
            }
            const int lr0 = (mt_w << 4) + (q << 2);   // local row base
            const float4 xv = *(const float4*)&x[t * BATCH + m0 + lr0];
#pragma unroll
            for (int e = 0; e < 4; ++e) {
                const float xe = (e == 0) ? xv.x : (e == 1) ? xv.y
                               : (e == 2) ? xv.z : xv.w;
                const float fg = sigmoidf_(z[0][e] + xe * wf + bf);
                const float ig = sigmoidf_(z[1][e] + xe * wi + bi);
                const float gg = tanhf_  (z[2][e] + xe * wg + bg);
                const float og = sigmoidf_(z[3][e] + xe * wo + bo);
                const float cn = gg * ig + creg[e] * fg;
                creg[e] = cn;
                Hs[(lr0 + e) * 32 + (p_w << 4) + l15] = (half_t)(tanhf_(cn) * og);
            }
        }
        __syncthreads();   // Hs complete

        // ---- coalesced h store: 1 u64/thread ----
        {
            const int r = tid >> 3, ch = tid & 7;
            const u64 v = *(const u64*)&Hs[r * 32 + ch * 4];
            u64* dst = (u64*)(hout + (size_t)(m0 + r) * HDIM + ubase + ch * 4);
            if (fast) *dst = v;   // normal store -> XCD-local L2 (L1 is WT)
            else __hip_atomic_store(dst, v, __ATOMIC_RELAXED,
                                    __HIP_MEMORY_SCOPE_AGENT);
        }
        asm volatile("s_waitcnt vmcnt(0)" ::: "memory");
        __syncthreads();   // all waves' h visible in (at least) this XCD's L2

        // ---- flag + poll: ALWAYS via LLC (R5-proven; no cached-spin risk) ----
        int* fl = &stepflags[(t << 8) + (group << 5)];
        if (tid == 0)
            __hip_atomic_store(&fl[slot], 1, __ATOMIC_RELAXED,
                               __HIP_MEMORY_SCOPE_AGENT);
        if (w == 0) {
            const int* pf = &fl[lane & 31];
            for (;;) {
                const int v = __hip_atomic_load(pf, __ATOMIC_RELAXED,
                                                __HIP_MEMORY_SCOPE_AGENT);
                if (__all(v == 1)) break;
                __builtin_amdgcn_s_sleep(1);
            }
        }
        asm volatile("" ::: "memory");
        __syncthreads();
    }

    // ---- fused projection + softmax: block -> batch row ----
    const int row = (group << 5) + slot;
    float* sm     = (float*)(smem + LDS_P_OFF);   // reuse P region
    float* hrow   = sm;
    float* psum   = sm + 1024;
    float* logits = sm + 1280;
    const half_t* hf = (const half_t*)(wsbase + (size_t)SEQ * HBUF_BYTES)
                     + ((size_t)row << 10);

    for (int k = tid; k < HDIM; k += 256) hrow[k] = (float)hf[k];
    __syncthreads();

    const int j = tid & 127, hlf = tid >> 7;
    const float4* wp = (const float4*)(Wph + (size_t)j * HDIM + hlf * 512);
    const float4* hp = (const float4*)(hrow + hlf * 512);
    float s = 0.0f;
#pragma unroll 8
    for (int k4 = 0; k4 < 128; ++k4) {
        const float4 wv = wp[k4];
        const float4 hv = hp[k4];
        s += wv.x * hv.x + wv.y * hv.y + wv.z * hv.z + wv.w * hv.w;
    }
    psum[tid] = s;
    __syncthreads();
    if (tid < ODIM) logits[tid] = psum[tid] + psum[tid + 128] + bph[tid];
    __syncthreads();
    if (tid < ODIM) {
        float mx = -1e30f;
        for (int i = 0; i < ODIM; ++i) mx = fmaxf(mx, logits[i]);
        psum[tid] = __expf(logits[tid] - mx);
    }
    __syncthreads();
    if (tid < ODIM) {
        float ssum = 0.0f;
        for (int i = 0; i < ODIM; ++i) ssum += psum[i];
        out[row * ODIM + tid] = psum[tid] / ssum;
    }
}

// ---------------------------------------------------------------------------
extern "C" void kernel_launch(void* const* d_in, const int* in_sizes, int n_in,
                              void* d_out, int out_size, void* d_ws, size_t ws_size,
                              hipStream_t stream) {
    const float* x   = (const float*)d_in[0];
    const float* Wfx = (const float*)d_in[1];
    const float* bfx = (const float*)d_in[2];
    const float* Wfh = (const float*)d_in[3];
    const float* bfh = (const float*)d_in[4];
    const float* Wix = (const float*)d_in[5];
    const float* bix = (const float*)d_in[6];
    const float* Wih = (const float*)d_in[7];
    const float* bih = (const float*)d_in[8];
    const float* Wgx = (const float*)d_in[9];
    const float* bgx = (const float*)d_in[10];
    const float* Wgh = (const float*)d_in[11];
    const float* bgh = (const float*)d_in[12];
    const float* Wox = (const float*)d_in[13];
    const float* box = (const float*)d_in[14];
    const float* Woh = (const float*)d_in[15];
    const float* boh = (const float*)d_in[16];
    const float* Wph = (const float*)d_in[17];
    const float* bph = (const float*)d_in[18];
    float* outp = (float*)d_out;

    char* ws = (char*)d_ws;
    int* zbase = (int*)(ws + FLAGS_OFF);

    lstm_init<<<(INIT_INTS + 255) / 256, 256, 0, stream>>>(zbase);

    (void)hipFuncSetAttribute((const void*)lstm_persist,
                              hipFuncAttributeMaxDynamicSharedMemorySize,
                              LDS_BYTES);

    void* args[] = {
        (void*)&x,
        (void*)&Wfh, (void*)&Wih, (void*)&Wgh, (void*)&Woh,
        (void*)&Wfx, (void*)&Wix, (void*)&Wgx, (void*)&Wox,
        (void*)&bfx, (void*)&bix, (void*)&bgx, (void*)&box,
        (void*)&bfh, (void*)&bih, (void*)&bgh, (void*)&boh,
        (void*)&Wph, (void*)&bph,
        (void*)&ws, (void*)&outp
    };
    hipError_t lerr = hipLaunchCooperativeKernel((const void*)lstm_persist,
                                                 dim3(NBLK), dim3(256),
                                                 args, LDS_BYTES, stream);
    if (lerr != hipSuccess) {
        // co-residency is structurally forced (130 KB LDS -> 1 block/CU,
        // 256 blocks on 256 CUs); the coop API was only validation.
        lstm_persist<<<dim3(NBLK), dim3(256), LDS_BYTES, stream>>>(
            x, Wfh, Wih, Wgh, Woh, Wfx, Wix, Wgx, Wox,
            bfx, bix, bgx, box, bfh, bih, bgh, boh,
            Wph, bph, ws, outp);
    }
}